// Round 12
// baseline (208.869 us; speedup 1.0000x reference)
//
#include <hip/hip_runtime.h>
#include <stdint.h>

typedef unsigned short u16;
typedef unsigned char u8;
using f32x4 = __attribute__((ext_vector_type(4))) float;
using s16x8 = __attribute__((ext_vector_type(8))) short;
using i32x4 = __attribute__((ext_vector_type(4))) int;
using i32x8 = __attribute__((ext_vector_type(8))) int;

__device__ __forceinline__ float bf2f(u16 u) {
  union { uint32_t u; float f; } v; v.u = ((uint32_t)u) << 16; return v.f;
}
__device__ __forceinline__ u16 f2bf(float f) {
  union { float f; uint32_t u; } v; v.f = f;
  uint32_t u = v.u;
  return (u16)((u + 0x7fffu + ((u >> 16) & 1u)) >> 16);
}

__device__ __forceinline__ void gload_lds16(const void* g, void* l) {
  __builtin_amdgcn_global_load_lds(
      (const __attribute__((address_space(1))) void*)g,
      (__attribute__((address_space(3))) void*)l, 16, 0, 0);
}

#define DSRO(dst, base, offbytes) \
  asm volatile("ds_read_b128 %0, %1 offset:%2" : "=v"(dst) : "v"(base), "i"(offbytes))

// ---------------- cast f32 -> bf16 (vectorized, grid-stride) ----------------
__global__ __launch_bounds__(256) void cast_bf16_kernel(
    const float* __restrict__ in, u16* __restrict__ out, int n8) {
  int idx = blockIdx.x * blockDim.x + threadIdx.x;
  int stride = gridDim.x * blockDim.x;
  for (int i = idx; i < n8; i += stride) {
    const float4* p = (const float4*)(in + (size_t)i * 8);
    float4 a = p[0], b = p[1];
    s16x8 o;
    o[0] = (short)f2bf(a.x); o[1] = (short)f2bf(a.y);
    o[2] = (short)f2bf(a.z); o[3] = (short)f2bf(a.w);
    o[4] = (short)f2bf(b.x); o[5] = (short)f2bf(b.y);
    o[6] = (short)f2bf(b.z); o[7] = (short)f2bf(b.w);
    *(s16x8*)(out + (size_t)i * 8) = o;
  }
}

// ------------- transpose-cast: W[K][N] f32 -> Wt[N][K] bf16 -----------------
__global__ __launch_bounds__(256) void tcast_kernel(
    const float* __restrict__ W, u16* __restrict__ Wt, int Kd, int Nd) {
  __shared__ u16 tile[32][33];
  int nbx = Nd / 32;
  int bx = blockIdx.x % nbx;
  int by = blockIdx.x / nbx;
  int tr = threadIdx.x >> 5;
  int tc = threadIdx.x & 31;
#pragma unroll
  for (int i = 0; i < 4; ++i)
    tile[tr + i * 8][tc] = f2bf(W[(size_t)(by * 32 + tr + i * 8) * Nd + bx * 32 + tc]);
  __syncthreads();
#pragma unroll
  for (int i = 0; i < 4; ++i)
    Wt[(size_t)(bx * 32 + tr + i * 8) * Kd + by * 32 + tc] = tile[tc][tr + i * 8];
}

// ============================ sync / gate macros ============================
#define GATE0 asm volatile("s_waitcnt vmcnt(0)" ::: "memory")
#define LGKM0 asm volatile("s_waitcnt lgkmcnt(0)" ::: "memory")
#define SBARA asm volatile("s_barrier" ::: "memory")
#define SCHED0 __builtin_amdgcn_sched_barrier(0)
#define NOSTG (void)0
#define NOTAIL (void)0
#define TAIL_G0 do { GATE0; SBARA; } while (0)

// ========== QK^T: 256x256 fp8 tile, BK=128; S8 = fp8(exp(/32)), rowsums =====
#define QSTG(buf, kt) do { \
    const u8* sa_ = Asrc + (size_t)(kt) * 128; \
    gload_lds16(sa_,                    &As8[buf][wave * 1024]); \
    gload_lds16(sa_ + (size_t)64 * Kd,  &As8[buf][wave * 1024 + 8192]); \
    gload_lds16(sa_ + (size_t)128 * Kd, &As8[buf][wave * 1024 + 16384]); \
    gload_lds16(sa_ + (size_t)192 * Kd, &As8[buf][wave * 1024 + 24576]); \
    const u8* sb_ = Bsrc + (size_t)(kt) * 128; \
    gload_lds16(sb_,                    &Bs8[buf][wave * 1024]); \
    gload_lds16(sb_ + (size_t)64 * Kd,  &Bs8[buf][wave * 1024 + 8192]); \
    gload_lds16(sb_ + (size_t)128 * Kd, &Bs8[buf][wave * 1024 + 16384]); \
    gload_lds16(sb_ + (size_t)192 * Kd, &Bs8[buf][wave * 1024 + 24576]); \
  } while (0)

#define QK2PH(buf, STAGE, TAIL) do { \
    i32x4 alo[4], ahi[4], blo[4], bhi[4]; \
    _Pragma("unroll") \
    for (int q = 0; q < 4; ++q) { \
      DSRO(alo[q], pvA[buf], q * 2048); \
      DSRO(ahi[q], pvA2[buf], q * 2048); \
      DSRO(blo[q], pvB[buf], q * 2048); \
      DSRO(bhi[q], pvB2[buf], q * 2048); \
    } \
    STAGE; \
    LGKM0; \
    SCHED0; \
    __builtin_amdgcn_s_setprio(1); \
    _Pragma("unroll") \
    for (int i2 = 0; i2 < 4; ++i2) { \
      i32x8 av = __builtin_shufflevector(alo[i2], ahi[i2], 0, 1, 2, 3, 4, 5, 6, 7); \
      _Pragma("unroll") \
      for (int j2 = 0; j2 < 4; ++j2) { \
        i32x8 bv = __builtin_shufflevector(blo[j2], bhi[j2], 0, 1, 2, 3, 4, 5, 6, 7); \
        acc[i2][j2] = __builtin_amdgcn_mfma_scale_f32_16x16x128_f8f6f4( \
            av, bv, acc[i2][j2], 0, 0, 0, 127, 0, 127); \
      } \
    } \
    __builtin_amdgcn_s_setprio(0); \
    SCHED0; \
    _Pragma("unroll") \
    for (int q = 0; q < 4; ++q) { \
      DSRO(blo[q], pvB[buf], (q + 4) * 2048); \
      DSRO(bhi[q], pvB2[buf], (q + 4) * 2048); \
    } \
    LGKM0; \
    SCHED0; \
    __builtin_amdgcn_s_setprio(1); \
    _Pragma("unroll") \
    for (int i2 = 0; i2 < 4; ++i2) { \
      i32x8 av = __builtin_shufflevector(alo[i2], ahi[i2], 0, 1, 2, 3, 4, 5, 6, 7); \
      _Pragma("unroll") \
      for (int j2 = 0; j2 < 4; ++j2) { \
        i32x8 bv = __builtin_shufflevector(blo[j2], bhi[j2], 0, 1, 2, 3, 4, 5, 6, 7); \
        acc[i2][4 + j2] = __builtin_amdgcn_mfma_scale_f32_16x16x128_f8f6f4( \
            av, bv, acc[i2][4 + j2], 0, 0, 0, 127, 0, 127); \
      } \
    } \
    __builtin_amdgcn_s_setprio(0); \
    SCHED0; \
    TAIL; \
  } while (0)

__global__ __launch_bounds__(512, 2) void gemm_qkt8(
    const u8* __restrict__ A, const u8* __restrict__ Bt, u8* __restrict__ C,
    float* __restrict__ sums, int M, int N, int Kd) {
  __shared__ u8 As8[2][256 * 128];  // 64 KiB
  __shared__ u8 Bs8[2][256 * 128];  // 64 KiB

  int bid = blockIdx.x;
  int swz = (bid & 7) * 64 + (bid >> 3);
  int bm = swz & 31;
  int bn = swz >> 5;
  size_t m0 = (size_t)bm << 8;
  size_t n0 = (size_t)bn << 8;

  int tid = threadIdx.x;
  int lane = tid & 63;
  int wave = tid >> 6;
  int wm = (wave >> 1) * 64;    // 4 M-groups of 64
  int wn = (wave & 1) * 128;    // 2 N-groups of 128
  int laneh = lane & 15;
  int lanev = lane >> 4;

  int prow = tid >> 3;
  int lslot = (tid & 7) ^ (prow & 7);
  const u8* Asrc = A + (m0 + prow) * Kd + lslot * 16;
  const u8* Bsrc = Bt + (n0 + prow) * Kd + lslot * 16;

  int arow = wm + laneh;
  int brow = wn + laneh;
  uint32_t pvA[2], pvA2[2], pvB[2], pvB2[2];
#pragma unroll
  for (int b = 0; b < 2; ++b) {
    pvA[b]  = (uint32_t)(uintptr_t)&As8[b][arow * 128 + (((2 * lanev) ^ (arow & 7)) * 16)];
    pvA2[b] = (uint32_t)(uintptr_t)&As8[b][arow * 128 + (((2 * lanev + 1) ^ (arow & 7)) * 16)];
    pvB[b]  = (uint32_t)(uintptr_t)&Bs8[b][brow * 128 + (((2 * lanev) ^ (brow & 7)) * 16)];
    pvB2[b] = (uint32_t)(uintptr_t)&Bs8[b][brow * 128 + (((2 * lanev + 1) ^ (brow & 7)) * 16)];
  }

  f32x4 acc[4][8] = {};

  QSTG(0, 0);
  GATE0;
  SBARA;

  int NI = Kd >> 7;  // 8
  for (int it = 0; it < (NI >> 1) - 1; ++it) {
    QK2PH(0, QSTG(1, 2 * it + 1), TAIL_G0);
    QK2PH(1, QSTG(0, 2 * it + 2), TAIL_G0);
  }
  QK2PH(0, QSTG(1, NI - 1), TAIL_G0);
  QK2PH(1, NOSTG, NOTAIL);

  SBARA;  // all waves done reading LDS before epilogue reuse

  // epilogue: exp -> fp8 via per-wave LDS bounce [64 rows][144 B stride]
  u8* epw = ((u8*)As8) + wave * 9216;
  int gcol0 = (int)n0 + wn;
#pragma unroll
  for (int mi = 0; mi < 4; ++mi)
#pragma unroll
    for (int r = 0; r < 4; ++r) {
      int base = (mi * 16 + lanev * 4 + r) * 144 + laneh;
#pragma unroll
      for (int jp = 0; jp < 4; ++jp) {
        float e0 = __expf(acc[mi][2 * jp][r] * 0.03125f);
        float e1 = __expf(acc[mi][2 * jp + 1][r] * 0.03125f);
        uint32_t p = (uint32_t)__builtin_amdgcn_cvt_pk_fp8_f32(e0, e1, 0, false);
        epw[base + 32 * jp]      = (u8)(p & 0xff);
        epw[base + 32 * jp + 16] = (u8)((p >> 8) & 0xff);
      }
    }
#pragma unroll
  for (int p = 0; p < 8; ++p) {
    int rowL = (lane >> 3) + 8 * p;
    uint4 v = *(const uint4*)&epw[rowL * 144 + (lane & 7) * 16];
    size_t grow = m0 + wm + rowL;
    *(uint4*)&C[grow * N + gcol0 + (lane & 7) * 16] = v;
    float s = 0.f;
    s += __builtin_amdgcn_cvt_f32_fp8((int)v.x, 0);
    s += __builtin_amdgcn_cvt_f32_fp8((int)v.x, 1);
    s += __builtin_amdgcn_cvt_f32_fp8((int)v.x, 2);
    s += __builtin_amdgcn_cvt_f32_fp8((int)v.x, 3);
    s += __builtin_amdgcn_cvt_f32_fp8((int)v.y, 0);
    s += __builtin_amdgcn_cvt_f32_fp8((int)v.y, 1);
    s += __builtin_amdgcn_cvt_f32_fp8((int)v.y, 2);
    s += __builtin_amdgcn_cvt_f32_fp8((int)v.y, 3);
    s += __builtin_amdgcn_cvt_f32_fp8((int)v.z, 0);
    s += __builtin_amdgcn_cvt_f32_fp8((int)v.z, 1);
    s += __builtin_amdgcn_cvt_f32_fp8((int)v.z, 2);
    s += __builtin_amdgcn_cvt_f32_fp8((int)v.z, 3);
    s += __builtin_amdgcn_cvt_f32_fp8((int)v.w, 0);
    s += __builtin_amdgcn_cvt_f32_fp8((int)v.w, 1);
    s += __builtin_amdgcn_cvt_f32_fp8((int)v.w, 2);
    s += __builtin_amdgcn_cvt_f32_fp8((int)v.w, 3);
    s += __shfl_xor(s, 1, 64);
    s += __shfl_xor(s, 2, 64);
    s += __shfl_xor(s, 4, 64);
    if ((lane & 7) == 0) atomicAdd(&sums[grow], s);
  }
}

// ================== PV fp8 MX GEMM: 256x128 tile, BK=128 ====================
#define PVSTG(buf, kt) do { \
    const u8* sa_ = Asrc + (size_t)(kt) * 128; \
    gload_lds16(sa_,                    &As8[buf][wave * 1024]); \
    gload_lds16(sa_ + (size_t)64 * Kd,  &As8[buf][wave * 1024 + 8192]); \
    gload_lds16(sa_ + (size_t)128 * Kd, &As8[buf][wave * 1024 + 16384]); \
    gload_lds16(sa_ + (size_t)192 * Kd, &As8[buf][wave * 1024 + 24576]); \
    const u8* sb_ = Bsrc + (size_t)(kt) * 128; \
    gload_lds16(sb_,                    &Bs8[buf][wave * 1024]); \
    gload_lds16(sb_ + (size_t)64 * Kd,  &Bs8[buf][wave * 1024 + 8192]); \
  } while (0)

#define PVPH(buf, STAGE, TAIL) do { \
    i32x4 alo[4], ahi[4], blo[4], bhi[4]; \
    _Pragma("unroll") \
    for (int q = 0; q < 4; ++q) { \
      DSRO(alo[q], pvA[buf], q * 2048); \
      DSRO(ahi[q], pvA2[buf], q * 2048); \
      DSRO(blo[q], pvB[buf], q * 2048); \
      DSRO(bhi[q], pvB2[buf], q * 2048); \
    } \
    STAGE; \
    LGKM0; \
    SCHED0; \
    __builtin_amdgcn_s_setprio(1); \
    _Pragma("unroll") \
    for (int i2 = 0; i2 < 4; ++i2) { \
      i32x8 av = __builtin_shufflevector(alo[i2], ahi[i2], 0, 1, 2, 3, 4, 5, 6, 7); \
      _Pragma("unroll") \
      for (int j2 = 0; j2 < 4; ++j2) { \
        i32x8 bv = __builtin_shufflevector(blo[j2], bhi[j2], 0, 1, 2, 3, 4, 5, 6, 7); \
        acc[i2][j2] = __builtin_amdgcn_mfma_scale_f32_16x16x128_f8f6f4( \
            av, bv, acc[i2][j2], 0, 0, 0, 127, 0, 127); \
      } \
    } \
    __builtin_amdgcn_s_setprio(0); \
    SCHED0; \
    TAIL; \
  } while (0)

__global__ __launch_bounds__(512, 2) void gemm_pv_fp8(
    const u8* __restrict__ A, const u8* __restrict__ Bt,
    float* __restrict__ C, const float* __restrict__ sums,
    const float* __restrict__ xres, int M, int N, int Kd) {
  __shared__ u8 As8[2][256 * 128];
  __shared__ u8 Bs8[2][128 * 128];

  int bid = blockIdx.x;
  int bm = (bid & 7) * 4 + ((bid >> 3) & 3);
  int bn = bid >> 5;
  size_t m0 = (size_t)bm << 8;
  size_t n0 = (size_t)bn << 7;

  int tid = threadIdx.x;
  int lane = tid & 63;
  int wave = tid >> 6;
  int wm = (wave >> 1) * 64;
  int wn = (wave & 1) * 64;
  int laneh = lane & 15;
  int lanev = lane >> 4;

  int prow = tid >> 3;
  int lslot = (tid & 7) ^ (prow & 7);
  const u8* Asrc = A + (m0 + prow) * Kd + lslot * 16;
  const u8* Bsrc = Bt + (n0 + prow) * Kd + lslot * 16;

  int arow = wm + laneh;
  int brow = wn + laneh;
  uint32_t pvA[2], pvA2[2], pvB[2], pvB2[2];
#pragma unroll
  for (int b = 0; b < 2; ++b) {
    pvA[b]  = (uint32_t)(uintptr_t)&As8[b][arow * 128 + (((2 * lanev) ^ (arow & 7)) * 16)];
    pvA2[b] = (uint32_t)(uintptr_t)&As8[b][arow * 128 + (((2 * lanev + 1) ^ (arow & 7)) * 16)];
    pvB[b]  = (uint32_t)(uintptr_t)&Bs8[b][brow * 128 + (((2 * lanev) ^ (brow & 7)) * 16)];
    pvB2[b] = (uint32_t)(uintptr_t)&Bs8[b][brow * 128 + (((2 * lanev + 1) ^ (brow & 7)) * 16)];
  }

  f32x4 acc[4][4] = {};

  PVSTG(0, 0);
  GATE0;
  SBARA;

  int NI = Kd >> 7;
  for (int it = 0; it < (NI >> 1) - 1; ++it) {
    PVPH(0, PVSTG(1, 2 * it + 1), TAIL_G0);
    PVPH(1, PVSTG(0, 2 * it + 2), TAIL_G0);
  }
  PVPH(0, PVSTG(1, NI - 1), TAIL_G0);
  PVPH(1, NOSTG, NOTAIL);

  int crow = (int)m0 + wm + (lanev << 2);
  int ccol = (int)n0 + wn + laneh;
#pragma unroll
  for (int mi = 0; mi < 4; ++mi)
#pragma unroll
    for (int r = 0; r < 4; ++r) {
      int row = crow + mi * 16 + r;
      float inv = 1.0f / sums[row];
      size_t rbase = (size_t)row * N + ccol;
#pragma unroll
      for (int ni = 0; ni < 4; ++ni)
        C[rbase + ni * 16] = xres[rbase + ni * 16] + acc[mi][ni][r] * inv;
    }
}

// ============== 4-phase 256x128 pipelined bf16 GEMM (Q-proj->fp8) ===========
#define PSTG(buf, h, kt) do { \
    const u16* sa_ = Asrc + (size_t)(kt) * 64 + (h) * 32; \
    gload_lds16(sa_, &As[buf][h][wave * 512]); \
    gload_lds16(sa_ + srow128, &As[buf][h][wave * 512 + 4096]); \
    const u16* sb_ = Bsrc + (size_t)(kt) * 64 + (h) * 32; \
    gload_lds16(sb_, &Bs[buf][h][wave * 512]); \
  } while (0)

#define STG_FULL(buf, kt) do { PSTG(buf, 0, kt); PSTG(buf, 1, kt); } while (0)

#define PPH(buf, kk, STAGE, TAIL) do { \
    DSRO(af[0], pA[buf][kk], 0); \
    DSRO(af[1], pA[buf][kk], 1024); \
    DSRO(af[2], pA[buf][kk], 2048); \
    DSRO(af[3], pA[buf][kk], 3072); \
    DSRO(bf[0], pB[buf][kk], 0); \
    DSRO(bf[1], pB[buf][kk], 1024); \
    DSRO(bf[2], pB[buf][kk], 2048); \
    DSRO(bf[3], pB[buf][kk], 3072); \
    STAGE; \
    LGKM0; \
    SCHED0; \
    __builtin_amdgcn_s_setprio(1); \
    _Pragma("unroll") \
    for (int i2 = 0; i2 < 4; ++i2) \
      _Pragma("unroll") \
      for (int j2 = 0; j2 < 4; ++j2) \
        acc[i2][j2] = __builtin_amdgcn_mfma_f32_16x16x32_bf16( \
            af[i2], bf[j2], acc[i2][j2], 0, 0, 0); \
    __builtin_amdgcn_s_setprio(0); \
    SCHED0; \
    TAIL; \
  } while (0)

__global__ __launch_bounds__(512, 2) void gemm_pipe_q(
    const u16* __restrict__ A, const u16* __restrict__ Bt,
    u8* __restrict__ Cout, const float* __restrict__ aux,
    int M, int N, int Kd) {
  __shared__ u16 As[2][2][256 * 32];
  __shared__ u16 Bs[2][2][128 * 32];

  int bid = blockIdx.x;
  int bm = (bid & 7) * 4 + ((bid >> 3) & 3);
  int bn = bid >> 5;
  size_t m0 = (size_t)bm << 8;
  size_t n0 = (size_t)bn << 7;

  int tid = threadIdx.x;
  int lane = tid & 63;
  int wave = tid >> 6;
  int wm = (wave >> 1) * 64;
  int wn = (wave & 1) * 64;
  int laneh = lane & 15;
  int lanev = lane >> 4;
  int aswz = ((lanev ^ ((laneh >> 1) & 3)) << 3);

  int prow = tid >> 2;
  int lslot = (tid & 3) ^ ((tid >> 3) & 3);
  const u16* Asrc = A + (m0 + prow) * Kd + lslot * 8;
  const u16* Bsrc = Bt + (n0 + prow) * Kd + lslot * 8;
  size_t srow128 = (size_t)128 * Kd;

  uint32_t pA[2][2], pB[2][2];
#pragma unroll
  for (int b = 0; b < 2; ++b)
#pragma unroll
    for (int k2 = 0; k2 < 2; ++k2) {
      pA[b][k2] = (uint32_t)(uintptr_t)&As[b][k2][(wm + laneh) * 32 + aswz];
      pB[b][k2] = (uint32_t)(uintptr_t)&Bs[b][k2][(wn + laneh) * 32 + aswz];
    }

  f32x4 acc[4][4] = {};
  s16x8 af[4], bf[4];

  STG_FULL(0, 0);
  GATE0;
  SBARA;

  int NI = Kd >> 7;
  for (int it = 0; it < NI - 1; ++it) {
    int t = 2 * it;
    PPH(0, 0, STG_FULL(1, t + 1), NOTAIL);
    PPH(0, 1, NOSTG, TAIL_G0);
    PPH(1, 0, STG_FULL(0, t + 2), NOTAIL);
    PPH(1, 1, NOSTG, TAIL_G0);
  }
  {
    int t = 2 * (NI - 1);
    PPH(0, 0, STG_FULL(1, t + 1), NOTAIL);
    PPH(0, 1, NOSTG, TAIL_G0);
    PPH(1, 0, NOSTG, NOTAIL);
    PPH(1, 1, NOSTG, NOTAIL);
  }

  int crow = (int)m0 + wm + (lanev << 2);
  int ccol = (int)n0 + wn + laneh;
#pragma unroll
  for (int mi = 0; mi < 4; ++mi)
#pragma unroll
    for (int r = 0; r < 4; ++r) {
      size_t row = (size_t)(crow + mi * 16 + r);
      float v0 = acc[mi][0][r] + aux[ccol];
      float v1 = acc[mi][1][r] + aux[ccol + 16];
      float v2 = acc[mi][2][r] + aux[ccol + 32];
      float v3 = acc[mi][3][r] + aux[ccol + 48];
      uint32_t p01 = (uint32_t)__builtin_amdgcn_cvt_pk_fp8_f32(v0, v1, 0, false);
      uint32_t p23 = (uint32_t)__builtin_amdgcn_cvt_pk_fp8_f32(v2, v3, 0, false);
      size_t base = row * N + ccol;
      Cout[base]      = (u8)(p01 & 0xff);
      Cout[base + 16] = (u8)((p01 >> 8) & 0xff);
      Cout[base + 32] = (u8)(p23 & 0xff);
      Cout[base + 48] = (u8)((p23 >> 8) & 0xff);
    }
}

// ------- NT GEMM 128^2, fp8 epilogues (K-proj flat / V-proj transposed) -----
template <int EPI>
__global__ __launch_bounds__(256) void gemm_nt(
    const u16* __restrict__ A, const u16* __restrict__ Bt,
    void* __restrict__ Cout, int M, int N, int K,
    const float* __restrict__ aux1) {
  constexpr int BK = 64;
  __shared__ u16 As[128 * BK];
  __shared__ u16 Bs[128 * BK];

  int nwg = gridDim.x;
  int bid = blockIdx.x;
  int swz = ((nwg & 7) == 0) ? ((bid & 7) * (nwg >> 3) + (bid >> 3)) : bid;
  int nbm = M >> 7;
  int bm = swz % nbm;
  int bn = swz / nbm;

  int tid = threadIdx.x;
  int lane = tid & 63;
  int wave = tid >> 6;
  int wm = (wave >> 1) << 6;
  int wn = (wave & 1) << 6;
  size_t m0 = (size_t)bm << 7;
  size_t n0 = (size_t)bn << 7;

  int srow = tid >> 3;
  int scol = (tid & 7) << 3;

  f32x4 acc[4][4] = {};

  const u16* Ag = A + (m0 + srow) * K + scol;
  const u16* Bg = Bt + (n0 + srow) * K + scol;
  u16* Asw = &As[wave * 512];
  u16* Bsw = &Bs[wave * 512];

  int laneh = lane & 15;
  int lanev = lane >> 4;

  for (int k0 = 0; k0 < K; k0 += BK) {
#pragma unroll
    for (int i = 0; i < 4; ++i) {
      gload_lds16(Ag + (size_t)i * 32 * K + k0, Asw + i * 2048);
      gload_lds16(Bg + (size_t)i * 32 * K + k0, Bsw + i * 2048);
    }
    __syncthreads();
#pragma unroll
    for (int kk = 0; kk < 2; ++kk) {
      s16x8 af[4], bfr[4];
#pragma unroll
      for (int i = 0; i < 4; ++i) {
        af[i]  = *(const s16x8*)&As[(wm + i * 16 + laneh) * BK + kk * 32 + lanev * 8];
        bfr[i] = *(const s16x8*)&Bs[(wn + i * 16 + laneh) * BK + kk * 32 + lanev * 8];
      }
#pragma unroll
      for (int mi = 0; mi < 4; ++mi)
#pragma unroll
        for (int ni = 0; ni < 4; ++ni)
          acc[mi][ni] = __builtin_amdgcn_mfma_f32_16x16x32_bf16(
              af[mi], bfr[ni], acc[mi][ni], 0, 0, 0);
    }
    __syncthreads();
  }

  int crow = (int)m0 + wm + (lanev << 2);
  int ccol = (int)n0 + wn + laneh;
  u8* C = (u8*)Cout;

  if constexpr (EPI == 0) {
#pragma unroll
    for (int mi = 0; mi < 4; ++mi)
#pragma unroll
      for (int r = 0; r < 4; ++r) {
        size_t row = (size_t)(crow + mi * 16 + r);
        float v0 = acc[mi][0][r] + aux1[ccol];
        float v1 = acc[mi][1][r] + aux1[ccol + 16];
        float v2 = acc[mi][2][r] + aux1[ccol + 32];
        float v3 = acc[mi][3][r] + aux1[ccol + 48];
        uint32_t p01 = (uint32_t)__builtin_amdgcn_cvt_pk_fp8_f32(v0, v1, 0, false);
        uint32_t p23 = (uint32_t)__builtin_amdgcn_cvt_pk_fp8_f32(v2, v3, 0, false);
        size_t base = row * N + ccol;
        C[base]      = (u8)(p01 & 0xff);
        C[base + 16] = (u8)((p01 >> 8) & 0xff);
        C[base + 32] = (u8)(p23 & 0xff);
        C[base + 48] = (u8)((p23 >> 8) & 0xff);
      }
  } else {
#pragma unroll
    for (int ni = 0; ni < 4; ++ni) {
      float b = aux1[ccol + ni * 16];
#pragma unroll
      for (int mi = 0; mi < 4; ++mi) {
        uint32_t w = (uint32_t)__builtin_amdgcn_cvt_pk_fp8_f32(
            acc[mi][ni][0] + b, acc[mi][ni][1] + b, 0, false);
        w = (uint32_t)__builtin_amdgcn_cvt_pk_fp8_f32(
            acc[mi][ni][2] + b, acc[mi][ni][3] + b, (int)w, true);
        *(uint32_t*)&C[(size_t)(ccol + ni * 16) * M + crow + mi * 16] = w;
      }
    }
  }
}

extern "C" void kernel_launch(void* const* d_in, const int* in_sizes, int n_in,
                              void* d_out, int out_size, void* d_ws, size_t ws_size,
                              hipStream_t stream) {
  const float* x  = (const float*)d_in[0];
  const float* mb = (const float*)d_in[1];
  const float* Wq = (const float*)d_in[2];
  const float* bq = (const float*)d_in[3];
  const float* Wk = (const float*)d_in[4];
  const float* bk = (const float*)d_in[5];
  const float* Wv = (const float*)d_in[6];
  const float* bv = (const float*)d_in[7];
  float* out = (float*)d_out;

  const int B = 8192, H = 1024, Mm = 4096;

  char* ws = (char*)d_ws;
  u16* xb  = (u16*)ws; ws += (size_t)B * H * 2;
  u16* mbb = (u16*)ws; ws += (size_t)Mm * H * 2;
  u16* Wqt = (u16*)ws; ws += (size_t)H * H * 2;
  u16* Wkt = (u16*)ws; ws += (size_t)H * H * 2;
  u16* Wvt = (u16*)ws; ws += (size_t)H * H * 2;
  u8*  Q8  = (u8*)ws;  ws += (size_t)B * H;
  u8*  K8  = (u8*)ws;  ws += (size_t)Mm * H;
  u8*  Vt8 = (u8*)ws;  ws += (size_t)H * Mm;
  u8*  S8  = (u8*)ws;  ws += (size_t)B * Mm;
  float* sums = (float*)ws;

  (void)hipMemsetAsync(sums, 0, (size_t)B * sizeof(float), stream);

  cast_bf16_kernel<<<2048, 256, 0, stream>>>(x, xb, B * H / 8);
  cast_bf16_kernel<<<1024, 256, 0, stream>>>(mb, mbb, Mm * H / 8);
  tcast_kernel<<<(H / 32) * (H / 32), 256, 0, stream>>>(Wq, Wqt, H, H);
  tcast_kernel<<<(H / 32) * (H / 32), 256, 0, stream>>>(Wk, Wkt, H, H);
  tcast_kernel<<<(H / 32) * (H / 32), 256, 0, stream>>>(Wv, Wvt, H, H);

  gemm_pipe_q<<<(B / 256) * (H / 128), 512, 0, stream>>>(xb, Wqt, Q8, bq, B, H, H);
  gemm_nt<0><<<(Mm / 128) * (H / 128), 256, 0, stream>>>(mbb, Wkt, K8, Mm, H, H, bk);
  gemm_nt<1><<<(Mm / 128) * (H / 128), 256, 0, stream>>>(mbb, Wvt, Vt8, Mm, H, H, bv);

  gemm_qkt8<<<(B / 256) * (Mm / 256), 512, 0, stream>>>(Q8, K8, S8, sums, B, Mm, H);

  gemm_pv_fp8<<<(B / 256) * (H / 128), 512, 0, stream>>>(S8, Vt8, out, sums, x, B, H, Mm);
}

// Round 13
// 141.545 us; speedup vs baseline: 1.4756x; 1.4756x over previous
//
#include <hip/hip_runtime.h>
#include <stdint.h>

typedef unsigned short u16;
typedef unsigned char u8;
using f32x4 = __attribute__((ext_vector_type(4))) float;
using i32x4 = __attribute__((ext_vector_type(4))) int;
using i32x8 = __attribute__((ext_vector_type(8))) int;

__device__ __forceinline__ void gload_lds16(const void* g, void* l) {
  __builtin_amdgcn_global_load_lds(
      (const __attribute__((address_space(1))) void*)g,
      (__attribute__((address_space(3))) void*)l, 16, 0, 0);
}

#define DSRO(dst, base, offbytes) \
  asm volatile("ds_read_b128 %0, %1 offset:%2" : "=v"(dst) : "v"(base), "i"(offbytes))

__device__ __forceinline__ u8 f2fp8(float v) {
  return (u8)((uint32_t)__builtin_amdgcn_cvt_pk_fp8_f32(v, 0.f, 0, false) & 0xff);
}

// ---------------- cast f32 -> fp8 (vectorized, grid-stride) -----------------
__global__ __launch_bounds__(256) void cast_fp8_kernel(
    const float* __restrict__ in, u8* __restrict__ out, int n8) {
  int idx = blockIdx.x * blockDim.x + threadIdx.x;
  int stride = gridDim.x * blockDim.x;
  for (int i = idx; i < n8; i += stride) {
    const float4* p = (const float4*)(in + (size_t)i * 8);
    float4 a = p[0], b = p[1];
    uint32_t w0 = (uint32_t)__builtin_amdgcn_cvt_pk_fp8_f32(a.x, a.y, 0, false);
    w0 = (uint32_t)__builtin_amdgcn_cvt_pk_fp8_f32(a.z, a.w, (int)w0, true);
    uint32_t w1 = (uint32_t)__builtin_amdgcn_cvt_pk_fp8_f32(b.x, b.y, 0, false);
    w1 = (uint32_t)__builtin_amdgcn_cvt_pk_fp8_f32(b.z, b.w, (int)w1, true);
    uint2 o; o.x = w0; o.y = w1;
    *(uint2*)(out + (size_t)i * 8) = o;
  }
}

// ------------- transpose-cast: W[K][N] f32 -> Wt8[N][K] fp8 -----------------
__global__ __launch_bounds__(256) void tcast_fp8_kernel(
    const float* __restrict__ W, u8* __restrict__ Wt, int Kd, int Nd) {
  __shared__ u8 tile[32][33];
  int nbx = Nd / 32;
  int bx = blockIdx.x % nbx;
  int by = blockIdx.x / nbx;
  int tr = threadIdx.x >> 5;
  int tc = threadIdx.x & 31;
#pragma unroll
  for (int i = 0; i < 4; ++i)
    tile[tr + i * 8][tc] = f2fp8(W[(size_t)(by * 32 + tr + i * 8) * Nd + bx * 32 + tc]);
  __syncthreads();
#pragma unroll
  for (int i = 0; i < 4; ++i)
    Wt[(size_t)(bx * 32 + tr + i * 8) * Kd + by * 32 + tc] = tile[tc][tr + i * 8];
}

// ============================ sync / gate macros ============================
#define GATE0 asm volatile("s_waitcnt vmcnt(0)" ::: "memory")
#define LGKM0 asm volatile("s_waitcnt lgkmcnt(0)" ::: "memory")
#define SBARA asm volatile("s_barrier" ::: "memory")
#define SCHED0 __builtin_amdgcn_sched_barrier(0)
#define NOSTG (void)0
#define NOTAIL (void)0
#define TAIL_G0 do { GATE0; SBARA; } while (0)

// ================== fp8 MX GEMM core: 256x128 tile, BK=128 =================
#define PVSTG(buf, kt) do { \
    const u8* sa_ = Asrc + (size_t)(kt) * 128; \
    gload_lds16(sa_,                    &As8[buf][wave * 1024]); \
    gload_lds16(sa_ + (size_t)64 * Kd,  &As8[buf][wave * 1024 + 8192]); \
    gload_lds16(sa_ + (size_t)128 * Kd, &As8[buf][wave * 1024 + 16384]); \
    gload_lds16(sa_ + (size_t)192 * Kd, &As8[buf][wave * 1024 + 24576]); \
    const u8* sb_ = Bsrc + (size_t)(kt) * 128; \
    gload_lds16(sb_,                    &Bs8[buf][wave * 1024]); \
    gload_lds16(sb_ + (size_t)64 * Kd,  &Bs8[buf][wave * 1024 + 8192]); \
  } while (0)

#define PVPH(buf, STAGE, TAIL) do { \
    i32x4 alo[4], ahi[4], blo[4], bhi[4]; \
    _Pragma("unroll") \
    for (int q = 0; q < 4; ++q) { \
      DSRO(alo[q], pvA[buf], q * 2048); \
      DSRO(ahi[q], pvA2[buf], q * 2048); \
      DSRO(blo[q], pvB[buf], q * 2048); \
      DSRO(bhi[q], pvB2[buf], q * 2048); \
    } \
    STAGE; \
    LGKM0; \
    SCHED0; \
    __builtin_amdgcn_s_setprio(1); \
    _Pragma("unroll") \
    for (int i2 = 0; i2 < 4; ++i2) { \
      i32x8 av = __builtin_shufflevector(alo[i2], ahi[i2], 0, 1, 2, 3, 4, 5, 6, 7); \
      _Pragma("unroll") \
      for (int j2 = 0; j2 < 4; ++j2) { \
        i32x8 bv = __builtin_shufflevector(blo[j2], bhi[j2], 0, 1, 2, 3, 4, 5, 6, 7); \
        acc[i2][j2] = __builtin_amdgcn_mfma_scale_f32_16x16x128_f8f6f4( \
            av, bv, acc[i2][j2], 0, 0, 0, 127, 0, 127); \
      } \
    } \
    __builtin_amdgcn_s_setprio(0); \
    SCHED0; \
    TAIL; \
  } while (0)

#define FP8GEMM_SETUP \
  int tid = threadIdx.x; \
  int lane = tid & 63; \
  int wave = tid >> 6; \
  int wm = (wave >> 1) * 64; \
  int wn = (wave & 1) * 64; \
  int laneh = lane & 15; \
  int lanev = lane >> 4; \
  int prow = tid >> 3; \
  int lslot = (tid & 7) ^ (prow & 7); \
  const u8* Asrc = A + (m0 + prow) * Kd + lslot * 16; \
  const u8* Bsrc = Bt + (n0 + prow) * Kd + lslot * 16; \
  int arow = wm + laneh; \
  int brow = wn + laneh; \
  uint32_t pvA[2], pvA2[2], pvB[2], pvB2[2]; \
  _Pragma("unroll") \
  for (int b = 0; b < 2; ++b) { \
    pvA[b]  = (uint32_t)(uintptr_t)&As8[b][arow * 128 + (((2 * lanev) ^ (arow & 7)) * 16)]; \
    pvA2[b] = (uint32_t)(uintptr_t)&As8[b][arow * 128 + (((2 * lanev + 1) ^ (arow & 7)) * 16)]; \
    pvB[b]  = (uint32_t)(uintptr_t)&Bs8[b][brow * 128 + (((2 * lanev) ^ (brow & 7)) * 16)]; \
    pvB2[b] = (uint32_t)(uintptr_t)&Bs8[b][brow * 128 + (((2 * lanev + 1) ^ (brow & 7)) * 16)]; \
  }

#define FP8GEMM_MAIN \
  PVSTG(0, 0); \
  GATE0; \
  SBARA; \
  int NI = Kd >> 7; \
  for (int it = 0; it < (NI >> 1) - 1; ++it) { \
    PVPH(0, PVSTG(1, 2 * it + 1), TAIL_G0); \
    PVPH(1, PVSTG(0, 2 * it + 2), TAIL_G0); \
  } \
  PVPH(0, PVSTG(1, NI - 1), TAIL_G0); \
  PVPH(1, NOSTG, NOTAIL);

// fp8 flat-store epilogue with bias (writes [M][N] fp8)
#define EPI_FP8_FLAT(DST, BIAS) do { \
    int crow = (int)m0 + wm + (lanev << 2); \
    int ccol = (int)n0 + wn + laneh; \
    _Pragma("unroll") \
    for (int mi = 0; mi < 4; ++mi) \
      _Pragma("unroll") \
      for (int r = 0; r < 4; ++r) { \
        size_t row = (size_t)(crow + mi * 16 + r); \
        float v0 = acc[mi][0][r] + BIAS[ccol]; \
        float v1 = acc[mi][1][r] + BIAS[ccol + 16]; \
        float v2 = acc[mi][2][r] + BIAS[ccol + 32]; \
        float v3 = acc[mi][3][r] + BIAS[ccol + 48]; \
        uint32_t p01 = (uint32_t)__builtin_amdgcn_cvt_pk_fp8_f32(v0, v1, 0, false); \
        uint32_t p23 = (uint32_t)__builtin_amdgcn_cvt_pk_fp8_f32(v2, v3, 0, false); \
        size_t base = row * N + ccol; \
        DST[base]      = (u8)(p01 & 0xff); \
        DST[base + 16] = (u8)((p01 >> 8) & 0xff); \
        DST[base + 32] = (u8)(p23 & 0xff); \
        DST[base + 48] = (u8)((p23 >> 8) & 0xff); \
      } \
  } while (0)

// ================= Q-proj: Q8 = fp8(x8 @ Wqt8^T + bq), 256x128 =============
__global__ __launch_bounds__(512, 2) void gemm_q8(
    const u8* __restrict__ A, const u8* __restrict__ Bt, u8* __restrict__ C,
    const float* __restrict__ bias, int M, int N, int Kd) {
  __shared__ u8 As8[2][256 * 128];
  __shared__ u8 Bs8[2][128 * 128];

  int bid = blockIdx.x;
  int bm = (bid & 7) * 4 + ((bid >> 3) & 3);
  int bn = bid >> 5;
  size_t m0 = (size_t)bm << 8;
  size_t n0 = (size_t)bn << 7;

  FP8GEMM_SETUP
  f32x4 acc[4][4] = {};
  FP8GEMM_MAIN
  EPI_FP8_FLAT(C, bias);
}

// ======= fused K/V proj: bid<128 -> K8 flat; bid>=128 -> Vt8 transposed =====
__global__ __launch_bounds__(512, 2) void gemm_kv8(
    const u8* __restrict__ mb8, const u8* __restrict__ Wkt8,
    const u8* __restrict__ Wvt8, u8* __restrict__ K8, u8* __restrict__ Vt8,
    const float* __restrict__ bk, const float* __restrict__ bv,
    int M, int N, int Kd) {
  __shared__ u8 As8[2][256 * 128];
  __shared__ u8 Bs8[2][128 * 128];

  int bid = blockIdx.x;
  int role = bid >> 7;
  int local = bid & 127;
  int bm = local & 15;
  int bn = local >> 4;
  size_t m0 = (size_t)bm << 8;
  size_t n0 = (size_t)bn << 7;

  const u8* A = mb8;
  const u8* Bt = role ? Wvt8 : Wkt8;

  FP8GEMM_SETUP
  f32x4 acc[4][4] = {};
  FP8GEMM_MAIN

  if (role == 0) {
    EPI_FP8_FLAT(K8, bk);
  } else {
    int crow = (int)m0 + wm + (lanev << 2);
    int ccol = (int)n0 + wn + laneh;
#pragma unroll
    for (int ni = 0; ni < 4; ++ni) {
      float b = bv[ccol + ni * 16];
#pragma unroll
      for (int mi = 0; mi < 4; ++mi) {
        uint32_t w = (uint32_t)__builtin_amdgcn_cvt_pk_fp8_f32(
            acc[mi][ni][0] + b, acc[mi][ni][1] + b, 0, false);
        w = (uint32_t)__builtin_amdgcn_cvt_pk_fp8_f32(
            acc[mi][ni][2] + b, acc[mi][ni][3] + b, (int)w, true);
        *(uint32_t*)&Vt8[(size_t)(ccol + ni * 16) * M + crow + mi * 16] = w;
      }
    }
  }
}

// ============ QK^T: S8 = fp8(exp((Q8@K8^T)/32)), rowsums (r11) ==============
__global__ __launch_bounds__(512, 2) void gemm_qkt8(
    const u8* __restrict__ A, const u8* __restrict__ Bt, u8* __restrict__ C,
    float* __restrict__ sums, int M, int N, int Kd) {
  __shared__ u8 As8[2][256 * 128];
  __shared__ u8 Bs8[2][128 * 128];

  int bid = blockIdx.x;
  int bm = (bid & 7) * 4 + ((bid >> 3) & 3);
  int bn = bid >> 5;
  size_t m0 = (size_t)bm << 8;
  size_t n0 = (size_t)bn << 7;

  FP8GEMM_SETUP
  f32x4 acc[4][4] = {};
  FP8GEMM_MAIN

  SBARA;  // all waves done reading LDS before epilogue reuse

  u8* epw = ((u8*)As8) + wave * 4608;  // [64 rows][72 B]
  int gcol0 = (int)n0 + wn;
#pragma unroll
  for (int mi = 0; mi < 4; ++mi)
#pragma unroll
    for (int r = 0; r < 4; ++r) {
      int rowL = mi * 16 + lanev * 4 + r;
      float e0 = __expf(acc[mi][0][r] * 0.03125f);
      float e1 = __expf(acc[mi][1][r] * 0.03125f);
      float e2 = __expf(acc[mi][2][r] * 0.03125f);
      float e3 = __expf(acc[mi][3][r] * 0.03125f);
      uint32_t p01 = (uint32_t)__builtin_amdgcn_cvt_pk_fp8_f32(e0, e1, 0, false);
      uint32_t p23 = (uint32_t)__builtin_amdgcn_cvt_pk_fp8_f32(e2, e3, 0, false);
      int base = rowL * 72 + laneh;
      epw[base]      = (u8)(p01 & 0xff);
      epw[base + 16] = (u8)((p01 >> 8) & 0xff);
      epw[base + 32] = (u8)(p23 & 0xff);
      epw[base + 48] = (u8)((p23 >> 8) & 0xff);
    }
#pragma unroll
  for (int p = 0; p < 4; ++p) {
    int rowL = (lane >> 2) + 16 * p;
    uint4 v = *(const uint4*)&epw[rowL * 72 + (lane & 3) * 16];
    size_t grow = m0 + wm + rowL;
    *(uint4*)&C[grow * N + gcol0 + (lane & 3) * 16] = v;
    float s = 0.f;
    s += __builtin_amdgcn_cvt_f32_fp8((int)v.x, 0);
    s += __builtin_amdgcn_cvt_f32_fp8((int)v.x, 1);
    s += __builtin_amdgcn_cvt_f32_fp8((int)v.x, 2);
    s += __builtin_amdgcn_cvt_f32_fp8((int)v.x, 3);
    s += __builtin_amdgcn_cvt_f32_fp8((int)v.y, 0);
    s += __builtin_amdgcn_cvt_f32_fp8((int)v.y, 1);
    s += __builtin_amdgcn_cvt_f32_fp8((int)v.y, 2);
    s += __builtin_amdgcn_cvt_f32_fp8((int)v.y, 3);
    s += __builtin_amdgcn_cvt_f32_fp8((int)v.z, 0);
    s += __builtin_amdgcn_cvt_f32_fp8((int)v.z, 1);
    s += __builtin_amdgcn_cvt_f32_fp8((int)v.z, 2);
    s += __builtin_amdgcn_cvt_f32_fp8((int)v.z, 3);
    s += __builtin_amdgcn_cvt_f32_fp8((int)v.w, 0);
    s += __builtin_amdgcn_cvt_f32_fp8((int)v.w, 1);
    s += __builtin_amdgcn_cvt_f32_fp8((int)v.w, 2);
    s += __builtin_amdgcn_cvt_f32_fp8((int)v.w, 3);
    s += __shfl_xor(s, 1, 64);
    s += __shfl_xor(s, 2, 64);
    if ((lane & 3) == 0) atomicAdd(&sums[grow], s);
  }
}

// =========== PV: C f32 = xres + (S8 @ Vt8^T) / sums[row] (r11) ==============
__global__ __launch_bounds__(512, 2) void gemm_pv_fp8(
    const u8* __restrict__ A, const u8* __restrict__ Bt,
    float* __restrict__ C, const float* __restrict__ sums,
    const float* __restrict__ xres, int M, int N, int Kd) {
  __shared__ u8 As8[2][256 * 128];
  __shared__ u8 Bs8[2][128 * 128];

  int bid = blockIdx.x;
  int bm = (bid & 7) * 4 + ((bid >> 3) & 3);
  int bn = bid >> 5;
  size_t m0 = (size_t)bm << 8;
  size_t n0 = (size_t)bn << 7;

  FP8GEMM_SETUP
  f32x4 acc[4][4] = {};
  FP8GEMM_MAIN

  int crow = (int)m0 + wm + (lanev << 2);
  int ccol = (int)n0 + wn + laneh;
#pragma unroll
  for (int mi = 0; mi < 4; ++mi)
#pragma unroll
    for (int r = 0; r < 4; ++r) {
      int row = crow + mi * 16 + r;
      float inv = 1.0f / sums[row];
      size_t rbase = (size_t)row * N + ccol;
#pragma unroll
      for (int ni = 0; ni < 4; ++ni)
        C[rbase + ni * 16] = xres[rbase + ni * 16] + acc[mi][ni][r] * inv;
    }
}

extern "C" void kernel_launch(void* const* d_in, const int* in_sizes, int n_in,
                              void* d_out, int out_size, void* d_ws, size_t ws_size,
                              hipStream_t stream) {
  const float* x  = (const float*)d_in[0];
  const float* mb = (const float*)d_in[1];
  const float* Wq = (const float*)d_in[2];
  const float* bq = (const float*)d_in[3];
  const float* Wk = (const float*)d_in[4];
  const float* bk = (const float*)d_in[5];
  const float* Wv = (const float*)d_in[6];
  const float* bv = (const float*)d_in[7];
  float* out = (float*)d_out;

  const int B = 8192, H = 1024, Mm = 4096;

  char* ws = (char*)d_ws;
  u8* x8   = (u8*)ws; ws += (size_t)B * H;
  u8* mb8  = (u8*)ws; ws += (size_t)Mm * H;
  u8* Wqt8 = (u8*)ws; ws += (size_t)H * H;
  u8* Wkt8 = (u8*)ws; ws += (size_t)H * H;
  u8* Wvt8 = (u8*)ws; ws += (size_t)H * H;
  u8* Q8   = (u8*)ws; ws += (size_t)B * H;
  u8* K8   = (u8*)ws; ws += (size_t)Mm * H;
  u8* Vt8  = (u8*)ws; ws += (size_t)H * Mm;
  u8* S8   = (u8*)ws; ws += (size_t)B * Mm;
  float* sums = (float*)ws;

  (void)hipMemsetAsync(sums, 0, (size_t)B * sizeof(float), stream);

  cast_fp8_kernel<<<2048, 256, 0, stream>>>(x, x8, B * H / 8);
  cast_fp8_kernel<<<1024, 256, 0, stream>>>(mb, mb8, Mm * H / 8);
  tcast_fp8_kernel<<<(H / 32) * (H / 32), 256, 0, stream>>>(Wq, Wqt8, H, H);
  tcast_fp8_kernel<<<(H / 32) * (H / 32), 256, 0, stream>>>(Wk, Wkt8, H, H);
  tcast_fp8_kernel<<<(H / 32) * (H / 32), 256, 0, stream>>>(Wv, Wvt8, H, H);

  gemm_q8<<<(B / 256) * (H / 128), 512, 0, stream>>>(x8, Wqt8, Q8, bq, B, H, H);
  gemm_kv8<<<2 * (Mm / 256) * (H / 128), 512, 0, stream>>>(
      mb8, Wkt8, Wvt8, K8, Vt8, bk, bv, Mm, H, H);

  gemm_qkt8<<<(B / 256) * (Mm / 128), 512, 0, stream>>>(Q8, K8, S8, sums, B, Mm, H);

  gemm_pv_fp8<<<(B / 256) * (H / 128), 512, 0, stream>>>(S8, Vt8, out, sums, x, B, H, Mm);
}